// Round 1
// baseline (6027.020 us; speedup 1.0000x reference)
//
#include <hip/hip_runtime.h>

#define NU 100000
#define NM 20000
#define NE 2000000
#define NL 500000
#define H  128

// ---------------------------------------------------------------- transpose
struct TDesc { const float* s; float* d; int R; int C; };
struct TPack { TDesc t[12]; };

__global__ __launch_bounds__(256) void transpose_all(TPack p) {
    TDesc d = p.t[blockIdx.y];
    int n = d.R * d.C;
    for (int i = blockIdx.x * 256 + threadIdx.x; i < n; i += gridDim.x * 256) {
        int r = i / d.C, c = i - r * d.C;
        d.d[c * d.R + r] = d.s[i];  // dst[k][h] = src[h][k]
    }
}

// ---------------------------------------------------------------- CSR build
__global__ __launch_bounds__(256) void deg_kernel(const int* __restrict__ ei,
                                                  int* rp_m, int* rp_u) {
    for (int i = blockIdx.x * 256 + threadIdx.x; i < NE; i += gridDim.x * 256) {
        int u = ei[i], m = ei[NE + i];
        atomicAdd(&rp_u[u + 1], 1);
        atomicAdd(&rp_m[m + 1], 1);
    }
}

__global__ __launch_bounds__(256) void scan2_kernel(int* rp_m, int n_m,
                                                    int* rp_u, int n_u) {
    int* a = (blockIdx.x == 0) ? rp_m : rp_u;
    int n  = (blockIdx.x == 0) ? n_m : n_u;
    __shared__ int s[256];
    __shared__ int carry;
    int tid = threadIdx.x;
    if (tid == 0) carry = 0;
    __syncthreads();
    for (int base = 0; base < n; base += 4096) {
        int v[16];
        int run = 0;
        int i0 = base + tid * 16;
#pragma unroll
        for (int i = 0; i < 16; ++i) {
            int x = (i0 + i < n) ? a[i0 + i] : 0;
            run += x; v[i] = run;
        }
        s[tid] = run;
        __syncthreads();
        for (int off = 1; off < 256; off <<= 1) {
            int t = (tid >= off) ? s[tid - off] : 0;
            __syncthreads();
            s[tid] += t;
            __syncthreads();
        }
        int prev = carry + (tid > 0 ? s[tid - 1] : 0);
#pragma unroll
        for (int i = 0; i < 16; ++i)
            if (i0 + i < n) a[i0 + i] = v[i] + prev;
        int total = s[255];
        __syncthreads();
        if (tid == 0) carry += total;
        __syncthreads();
    }
}

__global__ __launch_bounds__(256) void bucket_kernel(const int* __restrict__ ei,
        const int* __restrict__ rp_m, const int* __restrict__ rp_u,
        int* cur_m, int* cur_u, int* es_m, int* es_u) {
    for (int i = blockIdx.x * 256 + threadIdx.x; i < NE; i += gridDim.x * 256) {
        int u = ei[i], m = ei[NE + i];
        int pm = atomicAdd(&cur_m[m], 1);
        es_m[rp_m[m] + pm] = u;
        int pu = atomicAdd(&cur_u[u], 1);
        es_u[rp_u[u] + pu] = m;
    }
}

// ---------------------------------------------------------------- projection (Linear + BN(eval) + ReLU)
template <int K>
__global__ __launch_bounds__(256, 2) void proj_kernel(
        const float* __restrict__ x, const float* __restrict__ Wt,
        const float* __restrict__ lb, const float* __restrict__ g,
        const float* __restrict__ bb, const float* __restrict__ bm,
        const float* __restrict__ bv, float* __restrict__ out, int N) {
    __shared__ float sA[64 * K];
    const int tid = threadIdx.x;
    const int row0 = blockIdx.x * 64;
    constexpr int F4 = K / 4;
#pragma unroll
    for (int i = 0; i < (64 * F4) / 256; ++i) {
        int idx = tid + i * 256;
        int r = idx / F4, c = idx - r * F4;
        int gr = min(row0 + r, N - 1);
        ((float4*)sA)[idx] = ((const float4*)(x + (size_t)gr * K))[c];
    }
    __syncthreads();
    const int h_t = tid & 31, r_t = tid >> 5;
    float acc[8][4] = {};
#pragma unroll 4
    for (int k = 0; k < K; k += 4) {
        float4 w[4];
#pragma unroll
        for (int kk = 0; kk < 4; ++kk)
            w[kk] = *(const float4*)(Wt + (k + kk) * H + h_t * 4);
#pragma unroll
        for (int rr = 0; rr < 8; ++rr) {
            float4 a = *(const float4*)(sA + (r_t * 8 + rr) * K + k);
            acc[rr][0] += a.x * w[0].x + a.y * w[1].x + a.z * w[2].x + a.w * w[3].x;
            acc[rr][1] += a.x * w[0].y + a.y * w[1].y + a.z * w[2].y + a.w * w[3].y;
            acc[rr][2] += a.x * w[0].z + a.y * w[1].z + a.z * w[2].z + a.w * w[3].z;
            acc[rr][3] += a.x * w[0].w + a.y * w[1].w + a.z * w[2].w + a.w * w[3].w;
        }
    }
    const int h = h_t * 4;
    float4 lb4 = *(const float4*)(lb + h);
    float4 g4  = *(const float4*)(g  + h);
    float4 bb4 = *(const float4*)(bb + h);
    float4 m4  = *(const float4*)(bm + h);
    float4 v4  = *(const float4*)(bv + h);
    float sc[4] = { g4.x * rsqrtf(v4.x + 1e-5f), g4.y * rsqrtf(v4.y + 1e-5f),
                    g4.z * rsqrtf(v4.z + 1e-5f), g4.w * rsqrtf(v4.w + 1e-5f) };
    float lbv[4] = { lb4.x, lb4.y, lb4.z, lb4.w };
    float mv[4]  = { m4.x, m4.y, m4.z, m4.w };
    float bbv[4] = { bb4.x, bb4.y, bb4.z, bb4.w };
#pragma unroll
    for (int rr = 0; rr < 8; ++rr) {
        int gr = row0 + r_t * 8 + rr;
        if (gr < N) {
            float o[4];
#pragma unroll
            for (int c = 0; c < 4; ++c)
                o[c] = fmaxf((acc[rr][c] + lbv[c] - mv[c]) * sc[c] + bbv[c], 0.0f);
            *(float4*)(out + (size_t)gr * H + h) = make_float4(o[0], o[1], o[2], o[3]);
        }
    }
}

// ---------------------------------------------------------------- segment mean (CSR, no atomics)
__global__ __launch_bounds__(128) void agg_kernel(
        const float* __restrict__ src, const int* __restrict__ es,
        const int* __restrict__ rp, float* __restrict__ out) {
    __shared__ int sE[128];
    const int n = blockIdx.x;
    const int tid = threadIdx.x;
    const int start = rp[n], end = rp[n + 1];
    float acc = 0.0f;
    for (int base = start; base < end; base += 128) {
        int cnt = min(128, end - base);
        if (tid < cnt) sE[tid] = es[base + tid];
        __syncthreads();
        int j = 0;
        for (; j + 4 <= cnt; j += 4) {
            int s0 = sE[j], s1 = sE[j + 1], s2 = sE[j + 2], s3 = sE[j + 3];
            float a0 = src[(size_t)s0 * H + tid];
            float a1 = src[(size_t)s1 * H + tid];
            float a2 = src[(size_t)s2 * H + tid];
            float a3 = src[(size_t)s3 * H + tid];
            acc += a0; acc += a1; acc += a2; acc += a3;
        }
        for (; j < cnt; ++j) acc += src[(size_t)sE[j] * H + tid];
        __syncthreads();
    }
    int deg = end - start;
    float inv = deg > 0 ? 1.0f / (float)deg : 0.0f;
    out[(size_t)n * H + tid] = acc * inv;
}

// ---------------------------------------------------------------- SAGE linear: relu?(agg@Wl^T + bl + x@Wr^T)
__global__ __launch_bounds__(256, 2) void sage_kernel(
        const float* __restrict__ agg, const float* __restrict__ xdst,
        const float* __restrict__ Wlt, const float* __restrict__ Wrt,
        const float* __restrict__ bl, float* __restrict__ out, int N, int relu) {
    __shared__ float sA[64 * H];
    __shared__ float sB[64 * H];
    const int tid = threadIdx.x;
    const int row0 = blockIdx.x * 64;
#pragma unroll
    for (int i = 0; i < 8; ++i) {
        int idx = tid + i * 256;            // float4 index, 2048 total
        int r = idx >> 5, c4 = idx & 31;
        int gr = min(row0 + r, N - 1);
        ((float4*)sA)[idx] = ((const float4*)(agg  + (size_t)gr * H))[c4];
        ((float4*)sB)[idx] = ((const float4*)(xdst + (size_t)gr * H))[c4];
    }
    __syncthreads();
    const int h_t = tid & 31, r_t = tid >> 5;
    float acc[8][4] = {};
#pragma unroll 4
    for (int k = 0; k < H; k += 4) {
        float4 w[4];
#pragma unroll
        for (int kk = 0; kk < 4; ++kk)
            w[kk] = *(const float4*)(Wlt + (k + kk) * H + h_t * 4);
#pragma unroll
        for (int rr = 0; rr < 8; ++rr) {
            float4 a = *(const float4*)(sA + (r_t * 8 + rr) * H + k);
            acc[rr][0] += a.x * w[0].x + a.y * w[1].x + a.z * w[2].x + a.w * w[3].x;
            acc[rr][1] += a.x * w[0].y + a.y * w[1].y + a.z * w[2].y + a.w * w[3].y;
            acc[rr][2] += a.x * w[0].z + a.y * w[1].z + a.z * w[2].z + a.w * w[3].z;
            acc[rr][3] += a.x * w[0].w + a.y * w[1].w + a.z * w[2].w + a.w * w[3].w;
        }
    }
#pragma unroll 4
    for (int k = 0; k < H; k += 4) {
        float4 w[4];
#pragma unroll
        for (int kk = 0; kk < 4; ++kk)
            w[kk] = *(const float4*)(Wrt + (k + kk) * H + h_t * 4);
#pragma unroll
        for (int rr = 0; rr < 8; ++rr) {
            float4 a = *(const float4*)(sB + (r_t * 8 + rr) * H + k);
            acc[rr][0] += a.x * w[0].x + a.y * w[1].x + a.z * w[2].x + a.w * w[3].x;
            acc[rr][1] += a.x * w[0].y + a.y * w[1].y + a.z * w[2].y + a.w * w[3].y;
            acc[rr][2] += a.x * w[0].z + a.y * w[1].z + a.z * w[2].z + a.w * w[3].z;
            acc[rr][3] += a.x * w[0].w + a.y * w[1].w + a.z * w[2].w + a.w * w[3].w;
        }
    }
    float4 b4 = *(const float4*)(bl + h_t * 4);
    float bv[4] = { b4.x, b4.y, b4.z, b4.w };
#pragma unroll
    for (int rr = 0; rr < 8; ++rr) {
        int gr = row0 + r_t * 8 + rr;
        if (gr < N) {
            float o[4];
#pragma unroll
            for (int c = 0; c < 4; ++c) {
                float v = acc[rr][c] + bv[c];
                o[c] = relu ? fmaxf(v, 0.0f) : v;
            }
            *(float4*)(out + (size_t)gr * H + h_t * 4) = make_float4(o[0], o[1], o[2], o[3]);
        }
    }
}

// ---------------------------------------------------------------- fused edge decoder MLP
__global__ __launch_bounds__(256, 2) void decoder_kernel(
        const float* __restrict__ zu, const float* __restrict__ zm,
        const int* __restrict__ eli,
        const float* __restrict__ W1t, const float* __restrict__ b1,
        const float* __restrict__ W2t, const float* __restrict__ b2,
        const float* __restrict__ W3, const float* __restrict__ b3,
        float* __restrict__ out) {
    __shared__ float sF[32 * 256];   // feat, later h2
    __shared__ float sH[32 * 256];   // h1 half
    const int tid = threadIdx.x;
    const int row0 = blockIdx.x * 32;
    {   // gather feat = [zu[eu], zm[em]]
        int r = tid >> 3, p = tid & 7;
        int iu = eli[row0 + r];
        int im = eli[NL + row0 + r];
        const float4* zur = (const float4*)(zu + (size_t)iu * H);
        const float4* zmr = (const float4*)(zm + (size_t)im * H);
        float4* dF = ((float4*)sF) + r * 64;
#pragma unroll
        for (int j = 0; j < 4; ++j) dF[p + j * 8]      = zur[p + j * 8];
#pragma unroll
        for (int j = 0; j < 4; ++j) dF[32 + p + j * 8] = zmr[p + j * 8];
    }
    __syncthreads();
    const int h_t = tid & 31, r_t = tid >> 5;   // 32 col-threads x 8 row-threads(4 rows)
    float acc3[4][8] = {};
#pragma unroll 1
    for (int half = 0; half < 2; ++half) {
        // ---- h1half = ReLU(feat @ W1t[:, half*256 : half*256+256] + b1half)
        float acc2[4][8] = {};
#pragma unroll 4
        for (int k = 0; k < 256; k += 4) {
            float4 w0[4], w1[4];
#pragma unroll
            for (int kk = 0; kk < 4; ++kk) {
                const float* wr = W1t + (size_t)(k + kk) * 512 + half * 256 + h_t * 4;
                w0[kk] = *(const float4*)(wr);
                w1[kk] = *(const float4*)(wr + 128);
            }
#pragma unroll
            for (int rr = 0; rr < 4; ++rr) {
                float4 a = *(const float4*)(sF + (r_t * 4 + rr) * 256 + k);
                float av[4] = { a.x, a.y, a.z, a.w };
#pragma unroll
                for (int kk = 0; kk < 4; ++kk) {
                    acc2[rr][0] += av[kk] * w0[kk].x;
                    acc2[rr][1] += av[kk] * w0[kk].y;
                    acc2[rr][2] += av[kk] * w0[kk].z;
                    acc2[rr][3] += av[kk] * w0[kk].w;
                    acc2[rr][4] += av[kk] * w1[kk].x;
                    acc2[rr][5] += av[kk] * w1[kk].y;
                    acc2[rr][6] += av[kk] * w1[kk].z;
                    acc2[rr][7] += av[kk] * w1[kk].w;
                }
            }
        }
        {
            float4 bb0 = *(const float4*)(b1 + half * 256 + h_t * 4);
            float4 bb1 = *(const float4*)(b1 + half * 256 + 128 + h_t * 4);
#pragma unroll
            for (int rr = 0; rr < 4; ++rr) {
                float* dst = sH + (r_t * 4 + rr) * 256 + h_t * 4;
                *(float4*)dst = make_float4(
                    fmaxf(acc2[rr][0] + bb0.x, 0.0f), fmaxf(acc2[rr][1] + bb0.y, 0.0f),
                    fmaxf(acc2[rr][2] + bb0.z, 0.0f), fmaxf(acc2[rr][3] + bb0.w, 0.0f));
                *(float4*)(dst + 128) = make_float4(
                    fmaxf(acc2[rr][4] + bb1.x, 0.0f), fmaxf(acc2[rr][5] + bb1.y, 0.0f),
                    fmaxf(acc2[rr][6] + bb1.z, 0.0f), fmaxf(acc2[rr][7] + bb1.w, 0.0f));
            }
        }
        __syncthreads();
        // ---- acc3 += h1half @ W2t[half*256 : , :]
#pragma unroll 4
        for (int k = 0; k < 256; k += 4) {
            float4 w0[4], w1[4];
#pragma unroll
            for (int kk = 0; kk < 4; ++kk) {
                const float* wr = W2t + (size_t)(half * 256 + k + kk) * 256 + h_t * 4;
                w0[kk] = *(const float4*)(wr);
                w1[kk] = *(const float4*)(wr + 128);
            }
#pragma unroll
            for (int rr = 0; rr < 4; ++rr) {
                float4 a = *(const float4*)(sH + (r_t * 4 + rr) * 256 + k);
                float av[4] = { a.x, a.y, a.z, a.w };
#pragma unroll
                for (int kk = 0; kk < 4; ++kk) {
                    acc3[rr][0] += av[kk] * w0[kk].x;
                    acc3[rr][1] += av[kk] * w0[kk].y;
                    acc3[rr][2] += av[kk] * w0[kk].z;
                    acc3[rr][3] += av[kk] * w0[kk].w;
                    acc3[rr][4] += av[kk] * w1[kk].x;
                    acc3[rr][5] += av[kk] * w1[kk].y;
                    acc3[rr][6] += av[kk] * w1[kk].z;
                    acc3[rr][7] += av[kk] * w1[kk].w;
                }
            }
        }
        __syncthreads();  // before next half overwrites sH
    }
    // ---- h2 = ReLU(acc3 + b2) -> sF
    {
        float4 bb0 = *(const float4*)(b2 + h_t * 4);
        float4 bb1 = *(const float4*)(b2 + 128 + h_t * 4);
#pragma unroll
        for (int rr = 0; rr < 4; ++rr) {
            float* dst = sF + (r_t * 4 + rr) * 256 + h_t * 4;
            *(float4*)dst = make_float4(
                fmaxf(acc3[rr][0] + bb0.x, 0.0f), fmaxf(acc3[rr][1] + bb0.y, 0.0f),
                fmaxf(acc3[rr][2] + bb0.z, 0.0f), fmaxf(acc3[rr][3] + bb0.w, 0.0f));
            *(float4*)(dst + 128) = make_float4(
                fmaxf(acc3[rr][4] + bb1.x, 0.0f), fmaxf(acc3[rr][5] + bb1.y, 0.0f),
                fmaxf(acc3[rr][6] + bb1.z, 0.0f), fmaxf(acc3[rr][7] + bb1.w, 0.0f));
        }
    }
    __syncthreads();
    // ---- out = h2 @ W3^T + b3
    {
        int r = tid >> 3, p = tid & 7;
        float sum = 0.0f;
#pragma unroll
        for (int j = 0; j < 32; ++j) {
            int c = p * 32 + j;
            sum += sF[r * 256 + c] * W3[c];
        }
        sum += __shfl_down(sum, 4, 8);
        sum += __shfl_down(sum, 2, 8);
        sum += __shfl_down(sum, 1, 8);
        if (p == 0) out[row0 + r] = sum + b3[0];
    }
}

// ---------------------------------------------------------------- host
extern "C" void kernel_launch(void* const* d_in, const int* in_sizes, int n_in,
                              void* d_out, int out_size, void* d_ws, size_t ws_size,
                              hipStream_t stream) {
    const float* x_user  = (const float*)d_in[0];
    const float* x_movie = (const float*)d_in[1];
    const int*   ei      = (const int*)d_in[2];
    const int*   eli     = (const int*)d_in[3];
    const float* lin_u_W = (const float*)d_in[4];
    const float* lin_u_b = (const float*)d_in[5];
    const float* lin_m_W = (const float*)d_in[6];
    const float* lin_m_b = (const float*)d_in[7];
    const float* bn_u_g  = (const float*)d_in[8];
    const float* bn_u_b  = (const float*)d_in[9];
    const float* bn_u_m  = (const float*)d_in[10];
    const float* bn_u_v  = (const float*)d_in[11];
    const float* bn_m_g  = (const float*)d_in[12];
    const float* bn_m_b  = (const float*)d_in[13];
    const float* bn_m_m  = (const float*)d_in[14];
    const float* bn_m_v  = (const float*)d_in[15];
    const float* c1_um_Wl = (const float*)d_in[16];
    const float* c1_um_bl = (const float*)d_in[17];
    const float* c1_um_Wr = (const float*)d_in[18];
    const float* c1_mu_Wl = (const float*)d_in[19];
    const float* c1_mu_bl = (const float*)d_in[20];
    const float* c1_mu_Wr = (const float*)d_in[21];
    const float* c2_um_Wl = (const float*)d_in[22];
    const float* c2_um_bl = (const float*)d_in[23];
    const float* c2_um_Wr = (const float*)d_in[24];
    const float* c2_mu_Wl = (const float*)d_in[25];
    const float* c2_mu_bl = (const float*)d_in[26];
    const float* c2_mu_Wr = (const float*)d_in[27];
    const float* dec_W1 = (const float*)d_in[28];
    const float* dec_b1 = (const float*)d_in[29];
    const float* dec_W2 = (const float*)d_in[30];
    const float* dec_b2 = (const float*)d_in[31];
    const float* dec_W3 = (const float*)d_in[32];
    const float* dec_b3 = (const float*)d_in[33];

    char* base = (char*)d_ws;
    size_t off = 0;
    auto alloc = [&](size_t bytes) -> char* {
        char* p = base + off;
        off += (bytes + 255) & ~(size_t)255;
        return p;
    };
    float* xu   = (float*)alloc((size_t)NU * H * 4);
    float* xm   = (float*)alloc((size_t)NM * H * 4);
    float* xu1  = (float*)alloc((size_t)NU * H * 4);
    float* xm1  = (float*)alloc((size_t)NM * H * 4);
    float* aggu = (float*)alloc((size_t)NU * H * 4);
    float* aggm = (float*)alloc((size_t)NM * H * 4);
    float* wt_u = (float*)alloc((size_t)64 * H * 4);
    float* wt_m = (float*)alloc((size_t)H * H * 4);
    float* wt_s = (float*)alloc((size_t)8 * H * H * 4);
    float* w1t  = (float*)alloc((size_t)256 * 512 * 4);
    float* w2t  = (float*)alloc((size_t)512 * 256 * 4);
    int* rp_m  = (int*)alloc((size_t)(NM + 1) * 4);
    int* rp_u  = (int*)alloc((size_t)(NU + 1) * 4);
    int* cur_m = (int*)alloc((size_t)NM * 4);
    int* cur_u = (int*)alloc((size_t)NU * 4);
    int* es_m  = (int*)alloc((size_t)NE * 4);
    int* es_u  = (int*)alloc((size_t)NE * 4);
    float* zu = xu;   // xu dead before zu written
    float* zm = xm;   // xm dead before zm written
    const int HH = H * H;

    // zero CSR meta (rp_m .. cur_u incl. padding)
    hipMemsetAsync(rp_m, 0, (size_t)((char*)es_m - (char*)rp_m), stream);

    TPack tp;
    tp.t[0]  = { lin_u_W, wt_u, H, 64 };
    tp.t[1]  = { lin_m_W, wt_m, H, H };
    tp.t[2]  = { c1_um_Wl, wt_s + 0 * HH, H, H };
    tp.t[3]  = { c1_um_Wr, wt_s + 1 * HH, H, H };
    tp.t[4]  = { c1_mu_Wl, wt_s + 2 * HH, H, H };
    tp.t[5]  = { c1_mu_Wr, wt_s + 3 * HH, H, H };
    tp.t[6]  = { c2_um_Wl, wt_s + 4 * HH, H, H };
    tp.t[7]  = { c2_um_Wr, wt_s + 5 * HH, H, H };
    tp.t[8]  = { c2_mu_Wl, wt_s + 6 * HH, H, H };
    tp.t[9]  = { c2_mu_Wr, wt_s + 7 * HH, H, H };
    tp.t[10] = { dec_W1, w1t, 512, 256 };
    tp.t[11] = { dec_W2, w2t, 256, 512 };
    transpose_all<<<dim3(512, 12), 256, 0, stream>>>(tp);

    deg_kernel<<<2048, 256, 0, stream>>>(ei, rp_m, rp_u);
    scan2_kernel<<<2, 256, 0, stream>>>(rp_m, NM + 1, rp_u, NU + 1);
    bucket_kernel<<<2048, 256, 0, stream>>>(ei, rp_m, rp_u, cur_m, cur_u, es_m, es_u);

    proj_kernel<64><<<(NU + 63) / 64, 256, 0, stream>>>(
        x_user, wt_u, lin_u_b, bn_u_g, bn_u_b, bn_u_m, bn_u_v, xu, NU);
    proj_kernel<128><<<(NM + 63) / 64, 256, 0, stream>>>(
        x_movie, wt_m, lin_m_b, bn_m_g, bn_m_b, bn_m_m, bn_m_v, xm, NM);

    // conv1
    agg_kernel<<<NM, 128, 0, stream>>>(xu, es_m, rp_m, aggm);
    sage_kernel<<<(NM + 63) / 64, 256, 0, stream>>>(aggm, xm, wt_s + 0 * HH, wt_s + 1 * HH, c1_um_bl, xm1, NM, 1);
    agg_kernel<<<NU, 128, 0, stream>>>(xm, es_u, rp_u, aggu);
    sage_kernel<<<(NU + 63) / 64, 256, 0, stream>>>(aggu, xu, wt_s + 2 * HH, wt_s + 3 * HH, c1_mu_bl, xu1, NU, 1);
    // conv2
    agg_kernel<<<NM, 128, 0, stream>>>(xu1, es_m, rp_m, aggm);
    sage_kernel<<<(NM + 63) / 64, 256, 0, stream>>>(aggm, xm1, wt_s + 4 * HH, wt_s + 5 * HH, c2_um_bl, zm, NM, 0);
    agg_kernel<<<NU, 128, 0, stream>>>(xm1, es_u, rp_u, aggu);
    sage_kernel<<<(NU + 63) / 64, 256, 0, stream>>>(aggu, xu1, wt_s + 6 * HH, wt_s + 7 * HH, c2_mu_bl, zu, NU, 0);

    // decoder
    decoder_kernel<<<NL / 32, 256, 0, stream>>>(
        zu, zm, eli, w1t, dec_b1, w2t, dec_b2, dec_W3, dec_b3, (float*)d_out);
}

// Round 2
// 2514.226 us; speedup vs baseline: 2.3972x; 2.3972x over previous
//
#include <hip/hip_runtime.h>

#define NU 100000
#define NM 20000
#define NE 2000000
#define NL 500000
#define H  128

typedef __attribute__((ext_vector_type(8))) short bf16x8;   // 8 bf16 (4 VGPRs)
typedef __attribute__((ext_vector_type(4))) float floatx4;  // 4 fp32 acc

__device__ __forceinline__ unsigned short f2b(float x) {
    union { float f; unsigned u; } v; v.f = x;
    unsigned r = v.u + 0x7FFFu + ((v.u >> 16) & 1u);  // RNE
    return (unsigned short)(r >> 16);
}
__device__ __forceinline__ float b2f(unsigned short h) {
    union { unsigned u; float f; } v; v.u = ((unsigned)h) << 16;
    return v.f;
}

// ---------------------------------------------------------------- transpose
struct TDesc { const float* s; float* d; int R; int C; };
struct TPack { TDesc t[10]; };

__global__ __launch_bounds__(256) void transpose_all(TPack p) {
    TDesc d = p.t[blockIdx.y];
    int n = d.R * d.C;
    for (int i = blockIdx.x * 256 + threadIdx.x; i < n; i += gridDim.x * 256) {
        int r = i / d.C, c = i - r * d.C;
        d.d[c * d.R + r] = d.s[i];  // dst[k][h] = src[h][k]
    }
}

// ---------------------------------------------------------------- weight convert fp32 -> bf16 (native [out][in] layout)
__global__ __launch_bounds__(256) void cvt_weights(const float* __restrict__ W1,
                                                   const float* __restrict__ W2,
                                                   unsigned short* __restrict__ W1b,
                                                   unsigned short* __restrict__ W2b) {
    const int n = 512 * 256;  // both are 131072 elements
    for (int i = blockIdx.x * 256 + threadIdx.x; i < n; i += gridDim.x * 256) {
        W1b[i] = f2b(W1[i]);
        W2b[i] = f2b(W2[i]);
    }
}

// ---------------------------------------------------------------- CSR build
__global__ __launch_bounds__(256) void deg_kernel(const int* __restrict__ ei,
                                                  int* rp_m, int* rp_u) {
    for (int i = blockIdx.x * 256 + threadIdx.x; i < NE; i += gridDim.x * 256) {
        int u = ei[i], m = ei[NE + i];
        atomicAdd(&rp_u[u + 1], 1);
        atomicAdd(&rp_m[m + 1], 1);
    }
}

__global__ __launch_bounds__(256) void scan2_kernel(int* rp_m, int n_m,
                                                    int* rp_u, int n_u) {
    int* a = (blockIdx.x == 0) ? rp_m : rp_u;
    int n  = (blockIdx.x == 0) ? n_m : n_u;
    __shared__ int s[256];
    __shared__ int carry;
    int tid = threadIdx.x;
    if (tid == 0) carry = 0;
    __syncthreads();
    for (int base = 0; base < n; base += 4096) {
        int v[16];
        int run = 0;
        int i0 = base + tid * 16;
#pragma unroll
        for (int i = 0; i < 16; ++i) {
            int x = (i0 + i < n) ? a[i0 + i] : 0;
            run += x; v[i] = run;
        }
        s[tid] = run;
        __syncthreads();
        for (int off = 1; off < 256; off <<= 1) {
            int t = (tid >= off) ? s[tid - off] : 0;
            __syncthreads();
            s[tid] += t;
            __syncthreads();
        }
        int prev = carry + (tid > 0 ? s[tid - 1] : 0);
#pragma unroll
        for (int i = 0; i < 16; ++i)
            if (i0 + i < n) a[i0 + i] = v[i] + prev;
        int total = s[255];
        __syncthreads();
        if (tid == 0) carry += total;
        __syncthreads();
    }
}

__global__ __launch_bounds__(256) void bucket_kernel(const int* __restrict__ ei,
        const int* __restrict__ rp_m, const int* __restrict__ rp_u,
        int* cur_m, int* cur_u, int* es_m, int* es_u) {
    for (int i = blockIdx.x * 256 + threadIdx.x; i < NE; i += gridDim.x * 256) {
        int u = ei[i], m = ei[NE + i];
        int pm = atomicAdd(&cur_m[m], 1);
        es_m[rp_m[m] + pm] = u;
        int pu = atomicAdd(&cur_u[u], 1);
        es_u[rp_u[u] + pu] = m;
    }
}

// ---------------------------------------------------------------- projection (Linear + BN(eval) + ReLU)
template <int K>
__global__ __launch_bounds__(256, 2) void proj_kernel(
        const float* __restrict__ x, const float* __restrict__ Wt,
        const float* __restrict__ lb, const float* __restrict__ g,
        const float* __restrict__ bb, const float* __restrict__ bm,
        const float* __restrict__ bv, float* __restrict__ out, int N) {
    __shared__ float sA[64 * K];
    const int tid = threadIdx.x;
    const int row0 = blockIdx.x * 64;
    constexpr int F4 = K / 4;
#pragma unroll
    for (int i = 0; i < (64 * F4) / 256; ++i) {
        int idx = tid + i * 256;
        int r = idx / F4, c = idx - r * F4;
        int gr = min(row0 + r, N - 1);
        ((float4*)sA)[idx] = ((const float4*)(x + (size_t)gr * K))[c];
    }
    __syncthreads();
    const int h_t = tid & 31, r_t = tid >> 5;
    float acc[8][4] = {};
#pragma unroll 4
    for (int k = 0; k < K; k += 4) {
        float4 w[4];
#pragma unroll
        for (int kk = 0; kk < 4; ++kk)
            w[kk] = *(const float4*)(Wt + (k + kk) * H + h_t * 4);
#pragma unroll
        for (int rr = 0; rr < 8; ++rr) {
            float4 a = *(const float4*)(sA + (r_t * 8 + rr) * K + k);
            acc[rr][0] += a.x * w[0].x + a.y * w[1].x + a.z * w[2].x + a.w * w[3].x;
            acc[rr][1] += a.x * w[0].y + a.y * w[1].y + a.z * w[2].y + a.w * w[3].y;
            acc[rr][2] += a.x * w[0].z + a.y * w[1].z + a.z * w[2].z + a.w * w[3].z;
            acc[rr][3] += a.x * w[0].w + a.y * w[1].w + a.z * w[2].w + a.w * w[3].w;
        }
    }
    const int h = h_t * 4;
    float4 lb4 = *(const float4*)(lb + h);
    float4 g4  = *(const float4*)(g  + h);
    float4 bb4 = *(const float4*)(bb + h);
    float4 m4  = *(const float4*)(bm + h);
    float4 v4  = *(const float4*)(bv + h);
    float sc[4] = { g4.x * rsqrtf(v4.x + 1e-5f), g4.y * rsqrtf(v4.y + 1e-5f),
                    g4.z * rsqrtf(v4.z + 1e-5f), g4.w * rsqrtf(v4.w + 1e-5f) };
    float lbv[4] = { lb4.x, lb4.y, lb4.z, lb4.w };
    float mv[4]  = { m4.x, m4.y, m4.z, m4.w };
    float bbv[4] = { bb4.x, bb4.y, bb4.z, bb4.w };
#pragma unroll
    for (int rr = 0; rr < 8; ++rr) {
        int gr = row0 + r_t * 8 + rr;
        if (gr < N) {
            float o[4];
#pragma unroll
            for (int c = 0; c < 4; ++c)
                o[c] = fmaxf((acc[rr][c] + lbv[c] - mv[c]) * sc[c] + bbv[c], 0.0f);
            *(float4*)(out + (size_t)gr * H + h) = make_float4(o[0], o[1], o[2], o[3]);
        }
    }
}

// ---------------------------------------------------------------- segment mean (CSR, no atomics)
__global__ __launch_bounds__(128) void agg_kernel(
        const float* __restrict__ src, const int* __restrict__ es,
        const int* __restrict__ rp, float* __restrict__ out) {
    __shared__ int sE[128];
    const int n = blockIdx.x;
    const int tid = threadIdx.x;
    const int start = rp[n], end = rp[n + 1];
    float acc = 0.0f;
    for (int base = start; base < end; base += 128) {
        int cnt = min(128, end - base);
        if (tid < cnt) sE[tid] = es[base + tid];
        __syncthreads();
        int j = 0;
        for (; j + 4 <= cnt; j += 4) {
            int s0 = sE[j], s1 = sE[j + 1], s2 = sE[j + 2], s3 = sE[j + 3];
            float a0 = src[(size_t)s0 * H + tid];
            float a1 = src[(size_t)s1 * H + tid];
            float a2 = src[(size_t)s2 * H + tid];
            float a3 = src[(size_t)s3 * H + tid];
            acc += a0; acc += a1; acc += a2; acc += a3;
        }
        for (; j < cnt; ++j) acc += src[(size_t)sE[j] * H + tid];
        __syncthreads();
    }
    int deg = end - start;
    float inv = deg > 0 ? 1.0f / (float)deg : 0.0f;
    out[(size_t)n * H + tid] = acc * inv;
}

// ---------------------------------------------------------------- SAGE linear: relu?(agg@Wl^T + bl + x@Wr^T)
__global__ __launch_bounds__(256, 2) void sage_kernel(
        const float* __restrict__ agg, const float* __restrict__ xdst,
        const float* __restrict__ Wlt, const float* __restrict__ Wrt,
        const float* __restrict__ bl, float* __restrict__ out, int N, int relu) {
    __shared__ float sA[64 * H];
    __shared__ float sB[64 * H];
    const int tid = threadIdx.x;
    const int row0 = blockIdx.x * 64;
#pragma unroll
    for (int i = 0; i < 8; ++i) {
        int idx = tid + i * 256;            // float4 index, 2048 total
        int r = idx >> 5, c4 = idx & 31;
        int gr = min(row0 + r, N - 1);
        ((float4*)sA)[idx] = ((const float4*)(agg  + (size_t)gr * H))[c4];
        ((float4*)sB)[idx] = ((const float4*)(xdst + (size_t)gr * H))[c4];
    }
    __syncthreads();
    const int h_t = tid & 31, r_t = tid >> 5;
    float acc[8][4] = {};
#pragma unroll 4
    for (int k = 0; k < H; k += 4) {
        float4 w[4];
#pragma unroll
        for (int kk = 0; kk < 4; ++kk)
            w[kk] = *(const float4*)(Wlt + (k + kk) * H + h_t * 4);
#pragma unroll
        for (int rr = 0; rr < 8; ++rr) {
            float4 a = *(const float4*)(sA + (r_t * 8 + rr) * H + k);
            acc[rr][0] += a.x * w[0].x + a.y * w[1].x + a.z * w[2].x + a.w * w[3].x;
            acc[rr][1] += a.x * w[0].y + a.y * w[1].y + a.z * w[2].y + a.w * w[3].y;
            acc[rr][2] += a.x * w[0].z + a.y * w[1].z + a.z * w[2].z + a.w * w[3].z;
            acc[rr][3] += a.x * w[0].w + a.y * w[1].w + a.z * w[2].w + a.w * w[3].w;
        }
    }
#pragma unroll 4
    for (int k = 0; k < H; k += 4) {
        float4 w[4];
#pragma unroll
        for (int kk = 0; kk < 4; ++kk)
            w[kk] = *(const float4*)(Wrt + (k + kk) * H + h_t * 4);
#pragma unroll
        for (int rr = 0; rr < 8; ++rr) {
            float4 a = *(const float4*)(sB + (r_t * 8 + rr) * H + k);
            acc[rr][0] += a.x * w[0].x + a.y * w[1].x + a.z * w[2].x + a.w * w[3].x;
            acc[rr][1] += a.x * w[0].y + a.y * w[1].y + a.z * w[2].y + a.w * w[3].y;
            acc[rr][2] += a.x * w[0].z + a.y * w[1].z + a.z * w[2].z + a.w * w[3].z;
            acc[rr][3] += a.x * w[0].w + a.y * w[1].w + a.z * w[2].w + a.w * w[3].w;
        }
    }
    float4 b4 = *(const float4*)(bl + h_t * 4);
    float bv[4] = { b4.x, b4.y, b4.z, b4.w };
#pragma unroll
    for (int rr = 0; rr < 8; ++rr) {
        int gr = row0 + r_t * 8 + rr;
        if (gr < N) {
            float o[4];
#pragma unroll
            for (int c = 0; c < 4; ++c) {
                float v = acc[rr][c] + bv[c];
                o[c] = relu ? fmaxf(v, 0.0f) : v;
            }
            *(float4*)(out + (size_t)gr * H + h_t * 4) = make_float4(o[0], o[1], o[2], o[3]);
        }
    }
}

// ---------------------------------------------------------------- fused edge decoder MLP (bf16 MFMA)
// feat(32x256) @ W1^T -> ReLU -> (32x512) @ W2^T -> ReLU -> (32x256) @ W3^T
// A-frag: A[m=lane&15][k=(lane>>4)*8+j]; B-frag: B[n=lane&15][k=(lane>>4)*8+j]
// C/D:    col=lane&15, row=(lane>>4)*4+reg   (all verified learn_hip m89/m91)
#define SF_STRIDE 264   // 256 + 8 bf16 pad: row stride 528 B -> bank shift 4 -> 2-way (free)
#define SH_STRIDE 520   // 512 + 8 bf16 pad: 1040 B -> bank shift 4

__global__ __launch_bounds__(256, 3) void decoder_mfma(
        const float* __restrict__ zu, const float* __restrict__ zm,
        const int* __restrict__ eli,
        const unsigned short* __restrict__ W1b, const float* __restrict__ b1,
        const unsigned short* __restrict__ W2b, const float* __restrict__ b2,
        const float* __restrict__ W3, const float* __restrict__ b3,
        float* __restrict__ out) {
    __shared__ unsigned short sF[32 * SF_STRIDE];   // feat (bf16), later h2
    __shared__ unsigned short sH1[32 * SH_STRIDE];  // h1 (bf16)
    const int tid = threadIdx.x;
    const int row0 = blockIdx.x * 32;
    // ---- gather feat = [zu[eu] | zm[em]] fp32 -> bf16 into LDS
    {
        int r = tid >> 3, p = tid & 7;  // 32 rows x 8 col-chunks of 32
        int iu = eli[row0 + r];
        int im = eli[NL + row0 + r];
        const float4* zsrc = (p < 4) ? (const float4*)(zu + (size_t)iu * H)
                                     : (const float4*)(zm + (size_t)im * H);
        int c4 = (p & 3) * 8;  // float4 offset within the z row
        unsigned short* dst = sF + r * SF_STRIDE + p * 32;
#pragma unroll
        for (int j = 0; j < 8; ++j) {
            float4 v = zsrc[c4 + j];
            ushort4 o = { f2b(v.x), f2b(v.y), f2b(v.z), f2b(v.w) };
            *(ushort4*)(dst + j * 4) = o;
        }
    }
    __syncthreads();
    const int lane = tid & 63, w = tid >> 6;
    const int ln = lane & 15, lq = lane >> 4;
    // ---- layer 1: h1[32x512] — wave w owns n-cols [w*128, w*128+128)
    floatx4 acc1[8][2] = {};
    const unsigned short* w1p = W1b + (size_t)(w * 128 + ln) * 256 + lq * 8;
#pragma unroll 2
    for (int kg = 0; kg < 8; ++kg) {
        int k = kg * 32 + lq * 8;
        bf16x8 a0 = *(const bf16x8*)(sF + ln * SF_STRIDE + k);
        bf16x8 a1 = *(const bf16x8*)(sF + (16 + ln) * SF_STRIDE + k);
        const unsigned short* wp = w1p + kg * 32;
#pragma unroll
        for (int nt = 0; nt < 8; ++nt) {
            bf16x8 b = *(const bf16x8*)(wp + nt * 16 * 256);
            acc1[nt][0] = __builtin_amdgcn_mfma_f32_16x16x32_bf16(a0, b, acc1[nt][0], 0, 0, 0);
            acc1[nt][1] = __builtin_amdgcn_mfma_f32_16x16x32_bf16(a1, b, acc1[nt][1], 0, 0, 0);
        }
    }
    {   // epilogue: +b1, ReLU, store bf16 to sH1 in A-layout
        int rbase = lq * 4;
#pragma unroll
        for (int nt = 0; nt < 8; ++nt) {
            int n = w * 128 + nt * 16 + ln;
            float bv = b1[n];
#pragma unroll
            for (int mt = 0; mt < 2; ++mt)
#pragma unroll
                for (int r = 0; r < 4; ++r) {
                    float v = fmaxf(acc1[nt][mt][r] + bv, 0.0f);
                    sH1[(mt * 16 + rbase + r) * SH_STRIDE + n] = f2b(v);
                }
        }
    }
    __syncthreads();
    // ---- layer 2: h2[32x256] — wave w owns n-cols [w*64, w*64+64)
    floatx4 acc2[4][2] = {};
    const unsigned short* w2p = W2b + (size_t)(w * 64 + ln) * 512 + lq * 8;
#pragma unroll 2
    for (int kg = 0; kg < 16; ++kg) {
        int k = kg * 32 + lq * 8;
        bf16x8 a0 = *(const bf16x8*)(sH1 + ln * SH_STRIDE + k);
        bf16x8 a1 = *(const bf16x8*)(sH1 + (16 + ln) * SH_STRIDE + k);
        const unsigned short* wp = w2p + kg * 32;
#pragma unroll
        for (int nt = 0; nt < 4; ++nt) {
            bf16x8 b = *(const bf16x8*)(wp + (size_t)nt * 16 * 512);
            acc2[nt][0] = __builtin_amdgcn_mfma_f32_16x16x32_bf16(a0, b, acc2[nt][0], 0, 0, 0);
            acc2[nt][1] = __builtin_amdgcn_mfma_f32_16x16x32_bf16(a1, b, acc2[nt][1], 0, 0, 0);
        }
    }
    {   // epilogue: +b2, ReLU, store bf16 to sF (feat is dead) in A-layout
        int rbase = lq * 4;
#pragma unroll
        for (int nt = 0; nt < 4; ++nt) {
            int n = w * 64 + nt * 16 + ln;
            float bv = b2[n];
#pragma unroll
            for (int mt = 0; mt < 2; ++mt)
#pragma unroll
                for (int r = 0; r < 4; ++r) {
                    float v = fmaxf(acc2[nt][mt][r] + bv, 0.0f);
                    sF[(mt * 16 + rbase + r) * SF_STRIDE + n] = f2b(v);
                }
        }
    }
    __syncthreads();
    // ---- layer 3: out = h2 @ W3^T + b3
    {
        int r = tid >> 3, p = tid & 7;
        const unsigned short* hr = sF + r * SF_STRIDE + p * 32;
        const float* w3p = W3 + p * 32;
        float sum = 0.0f;
#pragma unroll
        for (int j = 0; j < 32; ++j) sum += b2f(hr[j]) * w3p[j];
        sum += __shfl_down(sum, 4, 8);
        sum += __shfl_down(sum, 2, 8);
        sum += __shfl_down(sum, 1, 8);
        if (p == 0) out[row0 + r] = sum + b3[0];
    }
}

// ---------------------------------------------------------------- host
extern "C" void kernel_launch(void* const* d_in, const int* in_sizes, int n_in,
                              void* d_out, int out_size, void* d_ws, size_t ws_size,
                              hipStream_t stream) {
    const float* x_user  = (const float*)d_in[0];
    const float* x_movie = (const float*)d_in[1];
    const int*   ei      = (const int*)d_in[2];
    const int*   eli     = (const int*)d_in[3];
    const float* lin_u_W = (const float*)d_in[4];
    const float* lin_u_b = (const float*)d_in[5];
    const float* lin_m_W = (const float*)d_in[6];
    const float* lin_m_b = (const float*)d_in[7];
    const float* bn_u_g  = (const float*)d_in[8];
    const float* bn_u_b  = (const float*)d_in[9];
    const float* bn_u_m  = (const float*)d_in[10];
    const float* bn_u_v  = (const float*)d_in[11];
    const float* bn_m_g  = (const float*)d_in[12];
    const float* bn_m_b  = (const float*)d_in[13];
    const float* bn_m_m  = (const float*)d_in[14];
    const float* bn_m_v  = (const float*)d_in[15];
    const float* c1_um_Wl = (const float*)d_in[16];
    const float* c1_um_bl = (const float*)d_in[17];
    const float* c1_um_Wr = (const float*)d_in[18];
    const float* c1_mu_Wl = (const float*)d_in[19];
    const float* c1_mu_bl = (const float*)d_in[20];
    const float* c1_mu_Wr = (const float*)d_in[21];
    const float* c2_um_Wl = (const float*)d_in[22];
    const float* c2_um_bl = (const float*)d_in[23];
    const float* c2_um_Wr = (const float*)d_in[24];
    const float* c2_mu_Wl = (const float*)d_in[25];
    const float* c2_mu_bl = (const float*)d_in[26];
    const float* c2_mu_Wr = (const float*)d_in[27];
    const float* dec_W1 = (const float*)d_in[28];
    const float* dec_b1 = (const float*)d_in[29];
    const float* dec_W2 = (const float*)d_in[30];
    const float* dec_b2 = (const float*)d_in[31];
    const float* dec_W3 = (const float*)d_in[32];
    const float* dec_b3 = (const float*)d_in[33];

    char* base = (char*)d_ws;
    size_t off = 0;
    auto alloc = [&](size_t bytes) -> char* {
        char* p = base + off;
        off += (bytes + 255) & ~(size_t)255;
        return p;
    };
    float* xu   = (float*)alloc((size_t)NU * H * 4);
    float* xm   = (float*)alloc((size_t)NM * H * 4);
    float* xu1  = (float*)alloc((size_t)NU * H * 4);
    float* xm1  = (float*)alloc((size_t)NM * H * 4);
    float* aggu = (float*)alloc((size_t)NU * H * 4);
    float* aggm = (float*)alloc((size_t)NM * H * 4);
    float* wt_u = (float*)alloc((size_t)64 * H * 4);
    float* wt_m = (float*)alloc((size_t)H * H * 4);
    float* wt_s = (float*)alloc((size_t)8 * H * H * 4);
    unsigned short* w1b = (unsigned short*)alloc((size_t)512 * 256 * 2);
    unsigned short* w2b = (unsigned short*)alloc((size_t)256 * 512 * 2);
    int* rp_m  = (int*)alloc((size_t)(NM + 1) * 4);
    int* rp_u  = (int*)alloc((size_t)(NU + 1) * 4);
    int* cur_m = (int*)alloc((size_t)NM * 4);
    int* cur_u = (int*)alloc((size_t)NU * 4);
    int* es_m  = (int*)alloc((size_t)NE * 4);
    int* es_u  = (int*)alloc((size_t)NE * 4);
    float* zu = xu;   // xu dead before zu written
    float* zm = xm;   // xm dead before zm written
    const int HH = H * H;

    // zero CSR meta (rp_m .. cur_u incl. padding)
    hipMemsetAsync(rp_m, 0, (size_t)((char*)es_m - (char*)rp_m), stream);

    TPack tp;
    tp.t[0]  = { lin_u_W, wt_u, H, 64 };
    tp.t[1]  = { lin_m_W, wt_m, H, H };
    tp.t[2]  = { c1_um_Wl, wt_s + 0 * HH, H, H };
    tp.t[3]  = { c1_um_Wr, wt_s + 1 * HH, H, H };
    tp.t[4]  = { c1_mu_Wl, wt_s + 2 * HH, H, H };
    tp.t[5]  = { c1_mu_Wr, wt_s + 3 * HH, H, H };
    tp.t[6]  = { c2_um_Wl, wt_s + 4 * HH, H, H };
    tp.t[7]  = { c2_um_Wr, wt_s + 5 * HH, H, H };
    tp.t[8]  = { c2_mu_Wl, wt_s + 6 * HH, H, H };
    tp.t[9]  = { c2_mu_Wr, wt_s + 7 * HH, H, H };
    transpose_all<<<dim3(256, 10), 256, 0, stream>>>(tp);
    cvt_weights<<<128, 256, 0, stream>>>(dec_W1, dec_W2, w1b, w2b);

    deg_kernel<<<2048, 256, 0, stream>>>(ei, rp_m, rp_u);
    scan2_kernel<<<2, 256, 0, stream>>>(rp_m, NM + 1, rp_u, NU + 1);
    bucket_kernel<<<2048, 256, 0, stream>>>(ei, rp_m, rp_u, cur_m, cur_u, es_m, es_u);

    proj_kernel<64><<<(NU + 63) / 64, 256, 0, stream>>>(
        x_user, wt_u, lin_u_b, bn_u_g, bn_u_b, bn_u_m, bn_u_v, xu, NU);
    proj_kernel<128><<<(NM + 63) / 64, 256, 0, stream>>>(
        x_movie, wt_m, lin_m_b, bn_m_g, bn_m_b, bn_m_m, bn_m_v, xm, NM);

    // conv1
    agg_kernel<<<NM, 128, 0, stream>>>(xu, es_m, rp_m, aggm);
    sage_kernel<<<(NM + 63) / 64, 256, 0, stream>>>(aggm, xm, wt_s + 0 * HH, wt_s + 1 * HH, c1_um_bl, xm1, NM, 1);
    agg_kernel<<<NU, 128, 0, stream>>>(xm, es_u, rp_u, aggu);
    sage_kernel<<<(NU + 63) / 64, 256, 0, stream>>>(aggu, xu, wt_s + 2 * HH, wt_s + 3 * HH, c1_mu_bl, xu1, NU, 1);
    // conv2
    agg_kernel<<<NM, 128, 0, stream>>>(xu1, es_m, rp_m, aggm);
    sage_kernel<<<(NM + 63) / 64, 256, 0, stream>>>(aggm, xm1, wt_s + 4 * HH, wt_s + 5 * HH, c2_um_bl, zm, NM, 0);
    agg_kernel<<<NU, 128, 0, stream>>>(xm1, es_u, rp_u, aggu);
    sage_kernel<<<(NU + 63) / 64, 256, 0, stream>>>(aggu, xu1, wt_s + 6 * HH, wt_s + 7 * HH, c2_mu_bl, zu, NU, 0);

    // decoder (bf16 MFMA, fused 3-layer MLP)
    decoder_mfma<<<NL / 32, 256, 0, stream>>>(
        zu, zm, eli, w1b, dec_b1, w2b, dec_b2, dec_W3, dec_b3, (float*)d_out);
}